// Round 9
// baseline (46.985 us; speedup 1.0000x reference)
//
#include <hip/hip_runtime.h>
#include <math.h>

typedef __attribute__((ext_vector_type(8))) short short8;
typedef __attribute__((ext_vector_type(4))) float f32x4;

namespace {
constexpr int NEL   = 4;
constexpr int NEXP  = 16;
constexpr int Bb    = 128;
constexpr int Aa    = 128;
constexpr int Cc    = 256;
constexpr int FATOM = 176;
constexpr int FPAIR = 32;
constexpr int FIN   = 384;
constexpr int HH1   = 128;
constexpr int HH2   = 96;
constexpr int NP    = Bb * Cc;                // 32768
constexpr int BUCKET_CAP = 4096;

// ws int offsets
constexpr int WS_COUNTS = 0;                  // 16 ints
constexpr int WS_BUCKET = 64;                 // 16 * 4096 ints

// per-expert LDS weight pack: W1 [12][128][32] | W2 [4][96][32] (bf16)
constexpr int W2_OFF = 12 * HH1 * 32;         // 49152 shorts
constexpr int WPK_E  = W2_OFF + 4 * HH2 * 32; // 61440 shorts (120 KB)
}

__device__ inline short f2bf(float f) {
    unsigned u = __builtin_bit_cast(unsigned, f);
    unsigned r = (u + 0x7FFFu + ((u >> 16) & 1u)) >> 16;
    return (short)r;
}
__device__ inline float celu1(float v) {
    return v > 0.f ? v : (__expf(v) - 1.0f);
}
__device__ inline short8 cvt8(const float* p) {
    float4 lo = *(const float4*)p;
    float4 hi = *(const float4*)(p + 4);
    short8 r;
    r[0] = f2bf(lo.x); r[1] = f2bf(lo.y); r[2] = f2bf(lo.z); r[3] = f2bf(lo.w);
    r[4] = f2bf(hi.x); r[5] = f2bf(hi.y); r[6] = f2bf(hi.z); r[7] = f2bf(hi.w);
    return r;
}

// ---- expert index + aggregated bucket append (proven path) ----
__global__ __launch_bounds__(256) void k_idx(
    const int* __restrict__ conn, const int* __restrict__ elements,
    int* __restrict__ counts, int* __restrict__ bucket,
    float* __restrict__ out)
{
    __shared__ int sh_cnt[NEXP], sh_base[NEXP];
    int t = threadIdx.x;
    int p = blockIdx.x * 256 + t;
    if (t < NEXP) sh_cnt[t] = 0;
    __syncthreads();
    int e = -1, r = 0;
    {
        int c0 = conn[2 * p], c1 = conn[2 * p + 1];
        if (c0 != -1) {
            int b = p / Cc;
            int i0 = b * Aa + c0; if (i0 < 0) i0 += Bb * Aa;
            int i1 = b * Aa + c1; if (i1 < 0) i1 += Bb * Aa;
            e = elements[i0] * NEL + elements[i1];
        }
        if (e < 0 || e >= NEXP) {
            out[2 * p] = 0.f; out[2 * p + 1] = 0.f;
            e = -1;
        } else {
            r = atomicAdd(&sh_cnt[e], 1);
        }
    }
    __syncthreads();
    if (t < NEXP) sh_base[t] = (sh_cnt[t] > 0) ? atomicAdd(&counts[t], sh_cnt[t]) : 0;
    __syncthreads();
    if (e >= 0) {
        int pos = sh_base[e] + r;
        if (pos < BUCKET_CAP) bucket[e * BUCKET_CAP + pos] = p;
    }
}

// ---- MFMA MoE: expert-persistent blocks; coalesced in-block W transpose ----
// grid = 256 blocks; e = bid & 15 (expert's 16 blocks share an XCD).
// 512 threads = 8 waves = 2 waves/SIMD; LDS 152 KB -> 1 block/CU.
__global__ __launch_bounds__(512, 2) void k_moe(
    const int* __restrict__ counts, const int* __restrict__ bucket,
    const int* __restrict__ conn,
    const float* __restrict__ sym, const float* __restrict__ pairf,
    const float* __restrict__ W1, const float* __restrict__ W2,
    const float* __restrict__ b1, const float* __restrict__ b2,
    const float* __restrict__ W3, const float* __restrict__ b3,
    float* __restrict__ out)
{
    __shared__ short Wlds[WPK_E];              // 120 KB
    __shared__ short H1s[8][16 * HH1];         // 32 KB, per-wave private, XOR-swizzled
    float* Tf = (float*)&H1s[0][0];            // 32x129 fp32 scratch (16.5 KB) overlay

    int e     = blockIdx.x & 15;
    int shard = blockIdx.x >> 4;
    int cnt = counts[e];
    if (cnt > BUCKET_CAP) cnt = BUCKET_CAP;

    int t = threadIdx.x;
    int w = t >> 6;
    int lane = t & 63;
    int lr = lane & 15, lg = (lane >> 4) & 3;

    // per-wave constants (issue early)
    float b1v[8];
#pragma unroll
    for (int j = 0; j < 8; ++j) b1v[j] = b1[e * HH1 + j * 16 + lr];
    float2 b3v = ((const float2*)b3)[e];

    // ---- W1: 12 chunks of [32k x 128n], coalesced load -> Tf -> packed Wlds ----
    {
        const float* W1e = W1 + (size_t)e * FIN * HH1;
        int q = t & 3, n = t >> 2;             // pack role: n in [0,128), q k-quad
#pragma unroll 1
        for (int ch = 0; ch < 12; ++ch) {
            const float* src = W1e + (size_t)ch * 32 * HH1;
#pragma unroll
            for (int ph = 0; ph < 2; ++ph) {
                int i = 4 * t + 2048 * ph;     // 4096 floats per chunk
                float4 v = *(const float4*)(src + i);
                int k = i >> 7, nn = i & 127;
                float* dst = &Tf[k * 129 + nn];
                dst[0] = v.x; dst[1] = v.y; dst[2] = v.z; dst[3] = v.w;
            }
            __syncthreads();
            short8 v;
#pragma unroll
            for (int j = 0; j < 8; ++j) v[j] = f2bf(Tf[(q * 8 + j) * 129 + n]);
            *(short8*)&Wlds[(ch * HH1 + n) * 32 + 8 * q] = v;
            __syncthreads();
        }
    }
    // ---- W2: 4 chunks of [32k x 96n] ----
    {
        const float* W2e = W2 + (size_t)e * HH1 * HH2;
        int q = t & 3, n2 = t >> 2;
#pragma unroll 1
        for (int ch = 0; ch < 4; ++ch) {
            const float* src = W2e + (size_t)ch * 32 * HH2;
            {
                int i = 4 * t;                 // 3072 floats per chunk
                if (i < 3072) {
                    float4 v = *(const float4*)(src + i);
                    int k = i / 96, nn = i - k * 96;
                    float* dst = &Tf[k * 129 + nn];
                    dst[0] = v.x; dst[1] = v.y; dst[2] = v.z; dst[3] = v.w;
                }
                int i2 = 2048 + 4 * t;
                if (t < 256) {
                    float4 v = *(const float4*)(src + i2);
                    int k = i2 / 96, nn = i2 - k * 96;
                    float* dst = &Tf[k * 129 + nn];
                    dst[0] = v.x; dst[1] = v.y; dst[2] = v.z; dst[3] = v.w;
                }
            }
            __syncthreads();
            if (t < 384) {
                short8 v;
#pragma unroll
                for (int j = 0; j < 8; ++j) v[j] = f2bf(Tf[(q * 8 + j) * 129 + n2]);
                *(short8*)&Wlds[W2_OFF + (ch * HH2 + n2) * 32 + 8 * q] = v;
            }
            __syncthreads();
        }
    }

    int nt = (cnt + 15) >> 4;
    const int* bucket_e = bucket + e * BUCKET_CAP;
    short* h1w = &H1s[w][0];

    for (int tile = shard * 8 + w; tile < nt; tile += 128) {
        int ii = tile * 16 + lr;
        int p = bucket_e[ii < cnt ? ii : cnt - 1];
        int2 c = ((const int2*)conn)[p];
        int bb = (p >> 8) << 7;                    // batch * Aa
        const float* fa = sym + (size_t)(bb + c.x) * FATOM;
        const float* fb = sym + (size_t)(bb + c.y) * FATOM;
        const float* pf = pairf + (size_t)p * FPAIR;

        // ---- A-gather: fp32 -> bf16 in-register, 12 fragments ----
        short8 a[12];
        a[0]  = cvt8(fa + 8 * lg);
        a[1]  = cvt8(fa + 32 + 8 * lg);
        a[2]  = cvt8(fa + 64 + 8 * lg);
        a[3]  = cvt8(fa + 96 + 8 * lg);
        a[4]  = cvt8(fa + 128 + 8 * lg);
        a[5]  = cvt8((lg < 2 ? fa + 160 : fb - 16) + 8 * lg);
        a[6]  = cvt8(fb + 16 + 8 * lg);
        a[7]  = cvt8(fb + 48 + 8 * lg);
        a[8]  = cvt8(fb + 80 + 8 * lg);
        a[9]  = cvt8(fb + 112 + 8 * lg);
        a[10] = cvt8(fb + 144 + 8 * lg);
        a[11] = cvt8(pf + 8 * lg);

        // ---- Layer 1: 16 pairs x 128 cols, W1 frags from LDS ----
        f32x4 acc[8];
#pragma unroll
        for (int j = 0; j < 8; ++j) acc[j] = (f32x4){b1v[j], b1v[j], b1v[j], b1v[j]};
#pragma unroll
        for (int ks = 0; ks < 12; ++ks) {
#pragma unroll
            for (int j = 0; j < 8; ++j) {
                short8 bw = *(const short8*)&Wlds[(ks * HH1 + j * 16 + lr) * 32 + 8 * lg];
                acc[j] = __builtin_amdgcn_mfma_f32_16x16x32_bf16(a[ks], bw, acc[j], 0, 0, 0);
            }
        }

        // ---- celu + swizzled H1 store (wave-private; no barrier) ----
#pragma unroll
        for (int j = 0; j < 8; ++j)
#pragma unroll
            for (int r2 = 0; r2 < 4; ++r2) {
                int m = 4 * lg + r2;
                int n = 16 * j + lr;
                h1w[m * HH1 + (((n >> 3) ^ (m & 7)) << 3) + (n & 7)] = f2bf(celu1(acc[j][r2]));
            }
        asm volatile("s_waitcnt lgkmcnt(0)" ::: "memory");
        __builtin_amdgcn_sched_barrier(0);

        // ---- Layer 2 (swapped) + Layer 3 in-register ----
        int mx = lr & 7;
        short8 bh[4];
#pragma unroll
        for (int q = 0; q < 4; ++q)
            bh[q] = *(const short8*)&h1w[lr * HH1 + (((q * 4 + lg) ^ mx) << 3)];

        float s0 = 0.f, s1 = 0.f;
#pragma unroll
        for (int t6 = 0; t6 < 6; ++t6) {
            int n2b = 16 * t6 + 4 * lg;
            float4 bb4 = *(const float4*)&b2[e * HH2 + n2b];
            f32x4 a2;
            a2[0] = bb4.x; a2[1] = bb4.y; a2[2] = bb4.z; a2[3] = bb4.w;
#pragma unroll
            for (int q = 0; q < 4; ++q) {
                short8 aw = *(const short8*)&Wlds[W2_OFF + (q * HH2 + 16 * t6 + lr) * 32 + 8 * lg];
                a2 = __builtin_amdgcn_mfma_f32_16x16x32_bf16(aw, bh[q], a2, 0, 0, 0);
            }
            float4 w3a = *(const float4*)&W3[(size_t)(e * HH2 + n2b) * 2];
            float4 w3b = *(const float4*)&W3[(size_t)(e * HH2 + n2b) * 2 + 4];
            float h0 = celu1(a2[0]), h1 = celu1(a2[1]), h2 = celu1(a2[2]), h3 = celu1(a2[3]);
            s0 = fmaf(h0, w3a.x, fmaf(h1, w3a.z, fmaf(h2, w3b.x, fmaf(h3, w3b.z, s0))));
            s1 = fmaf(h0, w3a.y, fmaf(h1, w3a.w, fmaf(h2, w3b.y, fmaf(h3, w3b.w, s1))));
        }
        s0 += __shfl_xor(s0, 16); s0 += __shfl_xor(s0, 32);
        s1 += __shfl_xor(s1, 16); s1 += __shfl_xor(s1, 32);
        if (((lane >> 4) & 3) == 0 && ii < cnt) {
            float2 o2; o2.x = s0 + b3v.x; o2.y = s1 + b3v.y;
            *(float2*)(out + 2 * (size_t)bucket_e[ii]) = o2;
        }
    }
}

extern "C" void kernel_launch(void* const* d_in, const int* in_sizes, int n_in,
                              void* d_out, int out_size, void* d_ws, size_t ws_size,
                              hipStream_t stream)
{
    const int*   elements = (const int*)d_in[0];
    const int*   conn     = (const int*)d_in[1];
    const float* sym      = (const float*)d_in[2];
    const float* pairf    = (const float*)d_in[3];
    const float* W1       = (const float*)d_in[4];
    const float* b1       = (const float*)d_in[5];
    const float* W2       = (const float*)d_in[6];
    const float* b2       = (const float*)d_in[7];
    const float* W3       = (const float*)d_in[8];
    const float* b3       = (const float*)d_in[9];
    float* out = (float*)d_out;

    int* wsi    = (int*)d_ws;
    int* counts = wsi + WS_COUNTS;
    int* bucket = wsi + WS_BUCKET;

    hipMemsetAsync((void*)counts, 0, NEXP * sizeof(int), stream);

    k_idx<<<NP / 256, 256, 0, stream>>>(conn, elements, counts, bucket, out);
    k_moe<<<256, 512, 0, stream>>>(counts, bucket, conn, sym, pairf,
                                   W1, W2, b1, b2, W3, b3, out);
}

// Round 10
// 35.308 us; speedup vs baseline: 1.3307x; 1.3307x over previous
//
#include <hip/hip_runtime.h>
#include <math.h>

typedef __attribute__((ext_vector_type(8))) short short8;
typedef __attribute__((ext_vector_type(4))) float f32x4;

namespace {
constexpr int NEL   = 4;
constexpr int NEXP  = 16;
constexpr int Bb    = 128;
constexpr int Aa    = 128;
constexpr int Cc    = 256;
constexpr int FATOM = 176;
constexpr int FPAIR = 32;
constexpr int FIN   = 384;
constexpr int HH1   = 128;
constexpr int HH2   = 96;
constexpr int NP    = Bb * Cc;                // 32768
constexpr int BUCKET_CAP = 4096;

// ws int offsets
constexpr int WS_COUNTS = 0;                  // 16 ints
constexpr int WS_BUCKET = 64;                 // 16 * 4096 ints
constexpr int WS_WPK    = 65600;              // shorts from (short*)(wsi + WS_WPK)

// per-expert packed weights (bf16): W1 [12][128][32] | W2 [4][96][32]
constexpr int W2_OFF = 12 * HH1 * 32;         // 49152 shorts
constexpr int WPK_E  = W2_OFF + 4 * HH2 * 32; // 61440 shorts (120 KB)

// prep grid: W1-pack | W2-pack | idx
constexpr int W1_BLOCKS  = 768;
constexpr int W2_BLOCKS  = 192;
constexpr int IDX_BLOCKS = NP / 256;          // 128
constexpr int W2_BASE  = W1_BLOCKS;           // 768
constexpr int IDX_BASE = W1_BLOCKS + W2_BLOCKS; // 960
constexpr int PREP_GRID = IDX_BASE + IDX_BLOCKS; // 1088
}

__device__ inline short f2bf(float f) {
    unsigned u = __builtin_bit_cast(unsigned, f);
    unsigned r = (u + 0x7FFFu + ((u >> 16) & 1u)) >> 16;
    return (short)r;
}
__device__ inline float celu1(float v) {
    return v > 0.f ? v : (__expf(v) - 1.0f);
}
__device__ inline short8 cvt8(const float* p) {
    float4 lo = *(const float4*)p;
    float4 hi = *(const float4*)(p + 4);
    short8 r;
    r[0] = f2bf(lo.x); r[1] = f2bf(lo.y); r[2] = f2bf(lo.z); r[3] = f2bf(lo.w);
    r[4] = f2bf(hi.x); r[5] = f2bf(hi.y); r[6] = f2bf(hi.z); r[7] = f2bf(hi.w);
    return r;
}

// ---- fused prep: W1 pack | W2 pack | expert index (all R5-proven paths) ----
__global__ __launch_bounds__(256) void k_prep(
    const float* __restrict__ W1, const float* __restrict__ W2,
    short* __restrict__ wpk,
    const int* __restrict__ conn, const int* __restrict__ elements,
    int* __restrict__ counts, int* __restrict__ bucket,
    float* __restrict__ out)
{
    __shared__ float T[32][33];
    __shared__ int sh_cnt[NEXP], sh_base[NEXP];

    int bid = blockIdx.x;
    int t = threadIdx.x;

    if (bid < IDX_BASE) {
        // LDS-tiled transpose+convert, coalesced both sides
        const float* src; short* dst; int N, k0, n0;
        if (bid < W2_BASE) {
            int e = bid / 48, tl = bid % 48;
            N = HH1; k0 = (tl % 12) * 32; n0 = (tl / 12) * 32;
            src = W1 + (size_t)e * FIN * HH1;
            dst = wpk + (size_t)e * WPK_E;
        } else {
            int b2i = bid - W2_BASE;
            int e = b2i / 12, tl = b2i % 12;
            N = HH2; k0 = (tl % 4) * 32; n0 = (tl / 4) * 32;
            src = W2 + (size_t)e * HH1 * HH2;
            dst = wpk + (size_t)e * WPK_E + W2_OFF;
        }
        int tx = t & 31, ty = t >> 5;
        int ks = k0 >> 5;
#pragma unroll
        for (int j = 0; j < 4; ++j) {
            int r = ty + 8 * j;
            T[r][tx] = src[(size_t)(k0 + r) * N + n0 + tx];
        }
        __syncthreads();
#pragma unroll
        for (int j = 0; j < 4; ++j) {
            int n = n0 + ty + 8 * j;
            dst[(size_t)(ks * N + n) * 32 + tx] = f2bf(T[tx][ty + 8 * j]);
        }
    } else {
        // expert index + aggregated bucket append
        int p = (bid - IDX_BASE) * 256 + t;
        if (t < NEXP) sh_cnt[t] = 0;
        __syncthreads();
        int e = -1, r = 0;
        {
            int c0 = conn[2 * p], c1 = conn[2 * p + 1];
            if (c0 != -1) {
                int b = p / Cc;
                int i0 = b * Aa + c0; if (i0 < 0) i0 += Bb * Aa;
                int i1 = b * Aa + c1; if (i1 < 0) i1 += Bb * Aa;
                e = elements[i0] * NEL + elements[i1];
            }
            if (e < 0 || e >= NEXP) {
                out[2 * p] = 0.f; out[2 * p + 1] = 0.f;
                e = -1;
            } else {
                r = atomicAdd(&sh_cnt[e], 1);
            }
        }
        __syncthreads();
        if (t < NEXP) sh_base[t] = (sh_cnt[t] > 0) ? atomicAdd(&counts[t], sh_cnt[t]) : 0;
        __syncthreads();
        if (e >= 0) {
            int pos = sh_base[e] + r;
            if (pos < BUCKET_CAP) bucket[e * BUCKET_CAP + pos] = p;
        }
    }
}

// ---- MFMA MoE: expert-persistent blocks; single-round-trip W staging;
//      first tile's gather chain overlapped with staging latency ----
__global__ __launch_bounds__(512, 2) void k_moe(
    const int* __restrict__ counts, const int* __restrict__ bucket,
    const int* __restrict__ conn,
    const float* __restrict__ sym, const float* __restrict__ pairf,
    const short* __restrict__ wpk,
    const float* __restrict__ b1, const float* __restrict__ b2,
    const float* __restrict__ W3, const float* __restrict__ b3,
    float* __restrict__ out)
{
    __shared__ short Wlds[WPK_E];              // 120 KB
    __shared__ short H1s[8][16 * HH1];         // 32 KB, per-wave private, XOR-swizzled

    int e     = blockIdx.x & 15;
    int shard = blockIdx.x >> 4;
    int cnt = counts[e];
    if (cnt > BUCKET_CAP) cnt = BUCKET_CAP;
    int nt = (cnt + 15) >> 4;

    int t = threadIdx.x;
    int w = t >> 6;
    int lane = t & 63;
    int lr = lane & 15, lg = (lane >> 4) & 3;

    const int* bucket_e = bucket + e * BUCKET_CAP;
    const short* wsrc = wpk + (size_t)e * WPK_E;

    // (1) W staging loads — issued first, stay in flight through (2)/(3)
    short8 v[15];
#pragma unroll
    for (int r = 0; r < 15; ++r) v[r] = *(const short8*)(wsrc + r * 4096 + t * 8);

    // (2) first-tile metadata chain (hides under W latency)
    int tile0 = shard * 8 + w;
    int ii0 = tile0 * 16 + lr;
    int idx0 = (tile0 < nt) ? (ii0 < cnt ? ii0 : (cnt > 0 ? cnt - 1 : 0)) : 0;
    int p0 = bucket_e[idx0] & (NP - 1);
    int2 c0 = ((const int2*)conn)[p0];

    // per-wave constants
    float b1v[8];
#pragma unroll
    for (int j = 0; j < 8; ++j) b1v[j] = b1[e * HH1 + j * 16 + lr];
    float2 b3v = ((const float2*)b3)[e];

    // (3) first-tile A-gather (fp32 -> bf16 in-register)
    short8 a0[12];
    {
        int bb = (p0 >> 8) << 7;
        const float* fa = sym + (size_t)(bb + (c0.x & 127)) * FATOM;
        const float* fb = sym + (size_t)(bb + (c0.y & 127)) * FATOM;
        const float* pf = pairf + (size_t)p0 * FPAIR;
        a0[0]  = cvt8(fa + 8 * lg);
        a0[1]  = cvt8(fa + 32 + 8 * lg);
        a0[2]  = cvt8(fa + 64 + 8 * lg);
        a0[3]  = cvt8(fa + 96 + 8 * lg);
        a0[4]  = cvt8(fa + 128 + 8 * lg);
        a0[5]  = cvt8((lg < 2 ? fa + 160 : fb - 16) + 8 * lg);
        a0[6]  = cvt8(fb + 16 + 8 * lg);
        a0[7]  = cvt8(fb + 48 + 8 * lg);
        a0[8]  = cvt8(fb + 80 + 8 * lg);
        a0[9]  = cvt8(fb + 112 + 8 * lg);
        a0[10] = cvt8(fb + 144 + 8 * lg);
        a0[11] = cvt8(pf + 8 * lg);
    }

    // (4) W LDS stores + single barrier
#pragma unroll
    for (int r = 0; r < 15; ++r) *(short8*)&Wlds[r * 4096 + t * 8] = v[r];
    __syncthreads();

    short* h1w = &H1s[w][0];

    auto do_tile = [&](const short8* a, int ii) {
        // ---- Layer 1: 16 pairs x 128 cols, W1 frags from LDS ----
        f32x4 acc[8];
#pragma unroll
        for (int j = 0; j < 8; ++j) acc[j] = (f32x4){b1v[j], b1v[j], b1v[j], b1v[j]};
#pragma unroll
        for (int ks = 0; ks < 12; ++ks) {
#pragma unroll
            for (int j = 0; j < 8; ++j) {
                short8 bw = *(const short8*)&Wlds[(ks * HH1 + j * 16 + lr) * 32 + 8 * lg];
                acc[j] = __builtin_amdgcn_mfma_f32_16x16x32_bf16(a[ks], bw, acc[j], 0, 0, 0);
            }
        }
        // ---- celu + swizzled H1 store (wave-private; no barrier) ----
#pragma unroll
        for (int j = 0; j < 8; ++j)
#pragma unroll
            for (int r2 = 0; r2 < 4; ++r2) {
                int m = 4 * lg + r2;
                int n = 16 * j + lr;
                h1w[m * HH1 + (((n >> 3) ^ (m & 7)) << 3) + (n & 7)] = f2bf(celu1(acc[j][r2]));
            }
        asm volatile("s_waitcnt lgkmcnt(0)" ::: "memory");
        __builtin_amdgcn_sched_barrier(0);

        // ---- Layer 2 (swapped) + Layer 3 in-register ----
        int mx = lr & 7;
        short8 bh[4];
#pragma unroll
        for (int q = 0; q < 4; ++q)
            bh[q] = *(const short8*)&h1w[lr * HH1 + (((q * 4 + lg) ^ mx) << 3)];

        float s0 = 0.f, s1 = 0.f;
#pragma unroll
        for (int t6 = 0; t6 < 6; ++t6) {
            int n2b = 16 * t6 + 4 * lg;
            float4 bb4 = *(const float4*)&b2[e * HH2 + n2b];
            f32x4 a2;
            a2[0] = bb4.x; a2[1] = bb4.y; a2[2] = bb4.z; a2[3] = bb4.w;
#pragma unroll
            for (int q = 0; q < 4; ++q) {
                short8 aw = *(const short8*)&Wlds[W2_OFF + (q * HH2 + 16 * t6 + lr) * 32 + 8 * lg];
                a2 = __builtin_amdgcn_mfma_f32_16x16x32_bf16(aw, bh[q], a2, 0, 0, 0);
            }
            float4 w3a = *(const float4*)&W3[(size_t)(e * HH2 + n2b) * 2];
            float4 w3b = *(const float4*)&W3[(size_t)(e * HH2 + n2b) * 2 + 4];
            float h0 = celu1(a2[0]), h1 = celu1(a2[1]), h2 = celu1(a2[2]), h3 = celu1(a2[3]);
            s0 = fmaf(h0, w3a.x, fmaf(h1, w3a.z, fmaf(h2, w3b.x, fmaf(h3, w3b.z, s0))));
            s1 = fmaf(h0, w3a.y, fmaf(h1, w3a.w, fmaf(h2, w3b.y, fmaf(h3, w3b.w, s1))));
        }
        s0 += __shfl_xor(s0, 16); s0 += __shfl_xor(s0, 32);
        s1 += __shfl_xor(s1, 16); s1 += __shfl_xor(s1, 32);
        if (((lane >> 4) & 3) == 0 && ii < cnt) {
            float2 o2; o2.x = s0 + b3v.x; o2.y = s1 + b3v.y;
            *(float2*)(out + 2 * (size_t)bucket_e[ii]) = o2;
        }
    };

    if (tile0 < nt) {
        do_tile(a0, ii0);
        // rare second pass (nt can slightly exceed 128)
        for (int tile = tile0 + 128; tile < nt; tile += 128) {
            int ii = tile * 16 + lr;
            int p = bucket_e[ii < cnt ? ii : cnt - 1] & (NP - 1);
            int2 c = ((const int2*)conn)[p];
            int bb = (p >> 8) << 7;
            const float* fa = sym + (size_t)(bb + (c.x & 127)) * FATOM;
            const float* fb = sym + (size_t)(bb + (c.y & 127)) * FATOM;
            const float* pf = pairf + (size_t)p * FPAIR;
            short8 a[12];
            a[0]  = cvt8(fa + 8 * lg);
            a[1]  = cvt8(fa + 32 + 8 * lg);
            a[2]  = cvt8(fa + 64 + 8 * lg);
            a[3]  = cvt8(fa + 96 + 8 * lg);
            a[4]  = cvt8(fa + 128 + 8 * lg);
            a[5]  = cvt8((lg < 2 ? fa + 160 : fb - 16) + 8 * lg);
            a[6]  = cvt8(fb + 16 + 8 * lg);
            a[7]  = cvt8(fb + 48 + 8 * lg);
            a[8]  = cvt8(fb + 80 + 8 * lg);
            a[9]  = cvt8(fb + 112 + 8 * lg);
            a[10] = cvt8(fb + 144 + 8 * lg);
            a[11] = cvt8(pf + 8 * lg);
            do_tile(a, ii);
        }
    }
}

extern "C" void kernel_launch(void* const* d_in, const int* in_sizes, int n_in,
                              void* d_out, int out_size, void* d_ws, size_t ws_size,
                              hipStream_t stream)
{
    const int*   elements = (const int*)d_in[0];
    const int*   conn     = (const int*)d_in[1];
    const float* sym      = (const float*)d_in[2];
    const float* pairf    = (const float*)d_in[3];
    const float* W1       = (const float*)d_in[4];
    const float* b1       = (const float*)d_in[5];
    const float* W2       = (const float*)d_in[6];
    const float* b2       = (const float*)d_in[7];
    const float* W3       = (const float*)d_in[8];
    const float* b3       = (const float*)d_in[9];
    float* out = (float*)d_out;

    int* wsi    = (int*)d_ws;
    int* counts = wsi + WS_COUNTS;
    int* bucket = wsi + WS_BUCKET;
    short* wpk  = (short*)(wsi + WS_WPK);

    hipMemsetAsync((void*)counts, 0, NEXP * sizeof(int), stream);

    k_prep<<<PREP_GRID, 256, 0, stream>>>(W1, W2, wpk, conn, elements,
                                          counts, bucket, out);
    k_moe<<<256, 512, 0, stream>>>(counts, bucket, conn, sym, pairf, wpk,
                                   b1, b2, W3, b3, out);
}